// Round 11
// baseline (1141.843 us; speedup 1.0000x reference)
//
#include <hip/hip_runtime.h>
#include <math.h>

// Problem constants (N=2, C=64, H=96, W=96, PATCH=3)
static constexpr int NITEM = 2;
static constexpr int C = 64;
static constexpr int H = 96;
static constexpr int W = 96;
static constexpr int HW = H * W;         // 9216 pixels
static constexpr int HP = 94;            // H - 3 + 1
static constexpr int NP = HP * HP;       // 8836 patch positions

// ---- factored-path constants ----
static constexpr int BRY = 8;                       // ref patch-rows per band (tier2)
static constexpr int NBAND = (HP + BRY - 1) / BRY;  // 12
static constexpr int PYB = BRY + 2;                 // pixel rows per band = 10
static constexpr int PROWS_B = PYB * W;             // 960 P rows per item per band
static constexpr int TSP = 128;                     // P tile
static constexpr int NPT = HW / TSP;                // 72 p-tiles (exact)
static constexpr int NQT_B = (PROWS_B + TSP - 1) / TSP; // 8 q-tiles (banded)
static constexpr int NQT_F = HW / TSP;              // 72 q-tiles (full)
static constexpr int ITILE = 256;                   // i's per pass2 block
static constexpr int NIT = (NP + ITILE - 1) / ITILE; // 35
static constexpr int PAD = 132;                     // LDS row pad

// ---- fallback (R4 direct) constants ----
static constexpr int NSEG = 8;
static constexpr int SEGLEN = (NP + NSEG - 1) / NSEG; // 1105
static constexpr int MT = 128;
static constexpr int NT = 128;
static constexpr int KC = 16;
static constexpr int LDP = MT + 4;
static constexpr int NMTILE = (NP + MT - 1) / MT;   // 70

// ---------------- Kernel 1: per-pixel channel L2 normalize + NCHW->NHWC ----------------
__global__ __launch_bounds__(256) void normalize_kernel(
    const float* __restrict__ f1, const float* __restrict__ f2,
    float* __restrict__ fiN, float* __restrict__ frN, float* __restrict__ ssn)
{
    int t = blockIdx.x * 256 + threadIdx.x;
    const int perTensor = NITEM * HW;
    if (t >= 2 * perTensor) return;
    int which = t / perTensor;
    int p = t - which * perTensor;
    int n = p / HW;
    int pix = p - n * HW;
    const float* src = (which ? f2 : f1) + (size_t)n * C * HW + pix;
    float s = 0.f;
    #pragma unroll
    for (int c = 0; c < C; c++) {
        float v = src[c * HW];
        s = fmaf(v, v, s);
    }
    float norm = sqrtf(s);
    float scale = 1.0f / fmaxf(norm, 1e-12f);
    float* dst = (which ? frN : fiN) + (size_t)p * C;
    #pragma unroll
    for (int c = 0; c < C; c++) {
        dst[c] = src[c * HW] * scale;
    }
    if (which) ssn[p] = s * scale * scale;
}

// ---------------- Kernel 2: ref patch inverse norms ----------------
__global__ __launch_bounds__(256) void refnorm_kernel(
    const float* __restrict__ ssn, float* __restrict__ invn)
{
    int t = blockIdx.x * 256 + threadIdx.x;
    if (t >= NITEM * NP) return;
    int n = t / NP;
    int r = t - n * NP;
    int yr = r / HP, xr = r - yr * HP;
    const float* s = ssn + n * HW;
    float acc = 0.f;
    #pragma unroll
    for (int dy = 0; dy < 3; dy++)
        #pragma unroll
        for (int dx = 0; dx < 3; dx++)
            acc += s[(yr + dy) * W + (xr + dx)];
    invn[t] = 1.0f / (sqrtf(acc) + 1e-5f);
}

// ================= FACTORED PATH (unified full-P / banded) =================
// Kernel A: GEMM writing RAW pixel-correlation P[q][p] (K=64).
// P[qL][p] = sum_c frN[ry0*W + qL][c] * fiN[p][c];  qL < prows.
// 512 threads, 128x128 tile -> acc 4x8/thread, ~70 VGPR, 2 blocks/CU = 4 waves/SIMD
// (vs 256-thread version: 2 waves/SIMD, ds_read latency exposed).
__global__ __launch_bounds__(512) void gemmP_kernel(
    const float* __restrict__ fiN, const float* __restrict__ frN,
    float* __restrict__ pmat, int ry0, int prows)
{
    __shared__ struct { float Aq[C][PAD]; float Bp[C][PAD]; } sm;  // 67584 B

    const int t = threadIdx.x;
    const int pt0 = blockIdx.x * TSP;    // input-pixel col base (128-aligned)
    const int qt0 = blockIdx.y * TSP;    // P-local q base
    const int n = blockIdx.z;

    const float* fa = frN + (size_t)n * HW * C;  // q side (ref)
    const float* fb = fiN + (size_t)n * HW * C;  // p side (input)

    // ---- stage panels: 512 threads, one row each, 4 float4/panel/thread.
    // channel map c0=(t&3)*4, cc=c0+16u -> LDS write bank 2-way max (free).
    {
        const int lrow = t >> 2;            // 0..127
        const int c0 = (t & 3) * 4;
        int qpix = ry0 * W + qt0 + lrow; if (qpix > HW - 1) qpix = HW - 1;
        int ppix = pt0 + lrow;           if (ppix > HW - 1) ppix = HW - 1;
        const float* qa = fa + (size_t)qpix * C + c0;
        const float* pb = fb + (size_t)ppix * C + c0;
        #pragma unroll
        for (int u = 0; u < 4; u++) {
            float4 va = *(const float4*)(qa + 16 * u);
            float4 vb = *(const float4*)(pb + 16 * u);
            int cc = c0 + 16 * u;
            sm.Aq[cc + 0][lrow] = va.x; sm.Aq[cc + 1][lrow] = va.y;
            sm.Aq[cc + 2][lrow] = va.z; sm.Aq[cc + 3][lrow] = va.w;
            sm.Bp[cc + 0][lrow] = vb.x; sm.Bp[cc + 1][lrow] = vb.y;
            sm.Bp[cc + 2][lrow] = vb.z; sm.Bp[cc + 3][lrow] = vb.w;
        }
    }
    __syncthreads();

    // ---- 128x128 GEMM, K=64. 4 q-rows x 8 p-cols per thread.
    const int tmq = (t >> 4) * 4;   // q fragment base: 0..124
    const int tnp = (t & 15) * 4;   // p fragment base: {0..60} + {64..124}
    float acc[4][8];
    #pragma unroll
    for (int i = 0; i < 4; i++)
        #pragma unroll
        for (int j = 0; j < 8; j++) acc[i][j] = 0.f;

    #pragma unroll 4
    for (int k = 0; k < C; k++) {
        float4 af = *(const float4*)&sm.Aq[k][tmq];
        float4 bf0 = *(const float4*)&sm.Bp[k][tnp];
        float4 bf1 = *(const float4*)&sm.Bp[k][tnp + 64];
        float av[4] = {af.x, af.y, af.z, af.w};
        float bw[8] = {bf0.x, bf0.y, bf0.z, bf0.w, bf1.x, bf1.y, bf1.z, bf1.w};
        #pragma unroll
        for (int i = 0; i < 4; i++)
            #pragma unroll
            for (int j = 0; j < 8; j++)
                acc[i][j] = fmaf(av[i], bw[j], acc[i][j]);
    }

    // ---- direct register->global stores (two float4 per q-row), fully coalesced
    float* pn = pmat + (size_t)n * prows * HW;
    #pragma unroll
    for (int i = 0; i < 4; i++) {
        int qL = qt0 + tmq + i;
        if (qL < prows) {
            float* row = pn + (size_t)qL * HW + pt0;
            *(float4*)(row + tnp)      = make_float4(acc[i][0], acc[i][1], acc[i][2], acc[i][3]);
            *(float4*)(row + tnp + 64) = make_float4(acc[i][4], acc[i][5], acc[i][6], acc[i][7]);
        }
    }
}

// Kernel B: full 3x3 DIAGONAL sum from raw P + patch-norm scale + per-ry argmax.
// term(dy,dx) = P[rowbase + dy*W + rx + dx][ppix + dy*W + dx],
// rowbase = blockIdx.x * W (band-local or global), ry = ry0 + blockIdx.x.
__global__ __launch_bounds__(256) void pass2_kernel(
    const float* __restrict__ pmat, const float* __restrict__ invn,
    float* __restrict__ pbv, int* __restrict__ pbi, int ry0, int prows)
{
    const int t = threadIdx.x;
    const int ryL = blockIdx.x;          // P-local ref patch-row
    const int ry = ry0 + ryL;            // global ref patch-row
    const int n = blockIdx.z;
    const int i = blockIdx.y * ITILE + t;
    if (i >= NP) return;

    const float* pn = pmat + (size_t)n * prows * HW;
    const float* inv = invn + (size_t)n * NP + ry * HP;
    const int rBase = ry * HP;

    int iy = i / HP, ix = i - iy * HP;
    int ppix = iy * W + ix;
    const float* b0 = pn + (size_t)(ryL * W) * HW + ppix;
    const float* b1 = b0 + (size_t)W * HW + W;
    const float* b2 = b1 + (size_t)W * HW + W;
    const size_t D = (size_t)HW + 1;     // diagonal stride (+1 row, +1 col)

    float bv = -INFINITY;
    int brx = 0;
    #pragma unroll 2
    for (int rx = 0; rx < HP; rx++) {
        size_t o = (size_t)rx * HW;
        float s0 = (b0[o] + b0[o + D]) + b0[o + 2 * D];
        float s1 = (b1[o] + b1[o + D]) + b1[o + 2 * D];
        float s2 = (b2[o] + b2[o + D]) + b2[o + 2 * D];
        float v = ((s0 + s1) + s2) * inv[rx];
        if (v > bv) { bv = v; brx = rx; }
    }
    size_t o = ((size_t)n * HP + ry) * NP + i;
    pbv[o] = bv;
    pbi[o] = rBase + brx;
}

// Reduce over 94 ry partials -> flow (lexicographic: first global max)
__global__ __launch_bounds__(256) void reduce94_kernel(
    const float* __restrict__ pbv, const int* __restrict__ pbi,
    float* __restrict__ flowh, float* __restrict__ floww)
{
    int t = blockIdx.x * 256 + threadIdx.x;
    if (t >= NITEM * NP) return;
    int n = t / NP;
    int i = t - n * NP;
    const float* bvp = pbv + (size_t)n * HP * NP;
    const int* bip = pbi + (size_t)n * HP * NP;
    float v = bvp[i];
    int idx = bip[i];
    for (int s = 1; s < HP; s++) {
        float v2 = bvp[(size_t)s * NP + i];
        int i2 = bip[(size_t)s * NP + i];
        if (v2 > v || (v2 == v && i2 < idx)) { v = v2; idx = i2; }
    }
    int yi = i / HP, xi = i - yi * HP;
    int yr = idx / HP, xr = idx - yr * HP;
    flowh[t] = (float)(yr - yi);
    floww[t] = (float)(xr - xi);
}

// ================= FALLBACK PATH (R4 direct, proven) =================
__global__ __launch_bounds__(256) void corr_kernel(
    const float* __restrict__ fiN, const float* __restrict__ frN,
    const float* __restrict__ invn,
    float* __restrict__ bestv, int* __restrict__ besti)
{
    __shared__ union SM {
        struct { float A[KC][LDP]; float B[KC][LDP]; } g;
        struct { float rv[MT][16]; int ri[MT][16]; } red;
    } sm;

    const int t = threadIdx.x;
    const int itile = blockIdx.x;
    const int seg = blockIdx.y;
    const int n = blockIdx.z;

    const float* fa = fiN + (size_t)n * HW * C;
    const float* fb = frN + (size_t)n * HW * C;
    const float* inv = invn + (size_t)n * NP;

    const int lrow = t >> 2;
    const int lc = (t & 3) * 4;

    int ia0 = itile * MT + lrow;      if (ia0 > NP - 1) ia0 = NP - 1;
    int ia1 = itile * MT + lrow + 64; if (ia1 > NP - 1) ia1 = NP - 1;
    const int ay0 = ia0 / HP, ax0 = ia0 - ay0 * HP;
    const int ay1 = ia1 / HP, ax1 = ia1 - ay1 * HP;
    const int aoff0 = (ay0 * W + ax0) * C;
    const int aoff1 = (ay1 * W + ax1) * C;

    const int tm4 = (t & 15) * 4;
    const int tn4 = (t >> 4) * 4;

    const int segStart = seg * SEGLEN;
    const int segEnd = (segStart + SEGLEN < NP) ? segStart + SEGLEN : NP;

    float bv[8];
    int bi[8];
    #pragma unroll
    for (int i = 0; i < 8; i++) { bv[i] = -INFINITY; bi[i] = 0; }

    for (int rt = segStart; rt < segEnd; rt += NT) {
        int ib0 = rt + lrow;      if (ib0 > NP - 1) ib0 = NP - 1;
        int ib1 = rt + lrow + 64; if (ib1 > NP - 1) ib1 = NP - 1;
        const int by0 = ib0 / HP, bx0 = ib0 - by0 * HP;
        const int by1 = ib1 / HP, bx1 = ib1 - by1 * HP;
        const int boff0 = (by0 * W + bx0) * C;
        const int boff1 = (by1 * W + bx1) * C;

        float acc[8][8];
        #pragma unroll
        for (int i = 0; i < 8; i++)
            #pragma unroll
            for (int j = 0; j < 8; j++) acc[i][j] = 0.f;

        float4 a0 = *(const float4*)(fa + aoff0 + lc);
        float4 a1 = *(const float4*)(fa + aoff1 + lc);
        float4 b0 = *(const float4*)(fb + boff0 + lc);
        float4 b1 = *(const float4*)(fb + boff1 + lc);

        #pragma unroll 1
        for (int ch = 0; ch < 36; ch++) {
            __syncthreads();
            sm.g.A[lc + 0][lrow] = a0.x; sm.g.A[lc + 1][lrow] = a0.y;
            sm.g.A[lc + 2][lrow] = a0.z; sm.g.A[lc + 3][lrow] = a0.w;
            sm.g.A[lc + 0][lrow + 64] = a1.x; sm.g.A[lc + 1][lrow + 64] = a1.y;
            sm.g.A[lc + 2][lrow + 64] = a1.z; sm.g.A[lc + 3][lrow + 64] = a1.w;
            sm.g.B[lc + 0][lrow] = b0.x; sm.g.B[lc + 1][lrow] = b0.y;
            sm.g.B[lc + 2][lrow] = b0.z; sm.g.B[lc + 3][lrow] = b0.w;
            sm.g.B[lc + 0][lrow + 64] = b1.x; sm.g.B[lc + 1][lrow + 64] = b1.y;
            sm.g.B[lc + 2][lrow + 64] = b1.z; sm.g.B[lc + 3][lrow + 64] = b1.w;
            __syncthreads();

            if (ch < 35) {
                const int chn = ch + 1;
                const int pp = chn >> 2;
                const int c0 = (chn & 3) << 4;
                const int dy = pp / 3, dx = pp - dy * 3;
                const int poff = (dy * W + dx) * C + c0 + lc;
                a0 = *(const float4*)(fa + aoff0 + poff);
                a1 = *(const float4*)(fa + aoff1 + poff);
                b0 = *(const float4*)(fb + boff0 + poff);
                b1 = *(const float4*)(fb + boff1 + poff);
            }

            #pragma unroll
            for (int k = 0; k < KC; k++) {
                float4 af0 = *(const float4*)&sm.g.A[k][tm4];
                float4 af1 = *(const float4*)&sm.g.A[k][tm4 + 64];
                float4 bf0 = *(const float4*)&sm.g.B[k][tn4];
                float4 bf1 = *(const float4*)&sm.g.B[k][tn4 + 64];
                float av[8] = {af0.x, af0.y, af0.z, af0.w, af1.x, af1.y, af1.z, af1.w};
                float bw[8] = {bf0.x, bf0.y, bf0.z, bf0.w, bf1.x, bf1.y, bf1.z, bf1.w};
                #pragma unroll
                for (int i = 0; i < 8; i++)
                    #pragma unroll
                    for (int j = 0; j < 8; j++)
                        acc[i][j] = fmaf(av[i], bw[j], acc[i][j]);
            }
        }

        #pragma unroll
        for (int j = 0; j < 8; j++) {
            int col = tn4 + ((j < 4) ? j : 60 + j);
            int r = rt + col;
            bool valid = (r < segEnd);
            float iv = inv[valid ? r : 0];
            #pragma unroll
            for (int i = 0; i < 8; i++) {
                float v = acc[i][j] * iv;
                if (valid && v > bv[i]) { bv[i] = v; bi[i] = r; }
            }
        }
    }

    __syncthreads();
    #pragma unroll
    for (int i = 0; i < 8; i++) {
        int row = tm4 + ((i < 4) ? i : 60 + i);
        sm.red.rv[row][t >> 4] = bv[i];
        sm.red.ri[row][t >> 4] = bi[i];
    }
    __syncthreads();
    if (t < MT) {
        float v = sm.red.rv[t][0];
        int idx = sm.red.ri[t][0];
        #pragma unroll
        for (int j = 1; j < 16; j++) {
            float v2 = sm.red.rv[t][j];
            int i2 = sm.red.ri[t][j];
            if (v2 > v || (v2 == v && i2 < idx)) { v = v2; idx = i2; }
        }
        int gi = itile * MT + t;
        if (gi < NP) {
            size_t o = ((size_t)n * NSEG + seg) * NP + gi;
            bestv[o] = v;
            besti[o] = idx;
        }
    }
}

__global__ __launch_bounds__(256) void reduce_flow_kernel(
    const float* __restrict__ bestv, const int* __restrict__ besti,
    float* __restrict__ flowh, float* __restrict__ floww)
{
    int t = blockIdx.x * 256 + threadIdx.x;
    if (t >= NITEM * NP) return;
    int n = t / NP;
    int i = t - n * NP;
    const float* bvp = bestv + (size_t)n * NSEG * NP;
    const int* bip = besti + (size_t)n * NSEG * NP;
    float v = bvp[i];
    int idx = bip[i];
    #pragma unroll
    for (int s = 1; s < NSEG; s++) {
        float v2 = bvp[s * NP + i];
        int i2 = bip[s * NP + i];
        if (v2 > v || (v2 == v && i2 < idx)) { v = v2; idx = i2; }
    }
    int yi = i / HP, xi = i - yi * HP;
    int yr = idx / HP, xr = idx - yr * HP;
    flowh[t] = (float)(yr - yi);
    floww[t] = (float)(xr - xi);
}

// ---------------- Kernel 5: expand to 9 shifted copies, channel-interleaved ----------------
__global__ __launch_bounds__(256) void expand_kernel(
    const float* __restrict__ flowh, const float* __restrict__ floww,
    float* __restrict__ out)
{
    int t = blockIdx.x * 256 + threadIdx.x;
    const int total = NITEM * 18 * HW;
    if (t >= total) return;
    int x = t % W;
    int y = (t / W) % H;
    int chn = (t / HW) % 18;
    int n = t / (18 * HW);
    int k = chn >> 1;
    int b = chn & 1;
    int is = k / 3, js = k - is * 3;
    int ys = y - is, xs = x - js;
    float val = 0.f;
    if (ys >= 0 && ys < HP && xs >= 0 && xs < HP) {
        int src = n * NP + ys * HP + xs;
        val = b ? floww[src] : flowh[src];
    }
    out[t] = val;
}

// ---------------- Launch ----------------
extern "C" void kernel_launch(void* const* d_in, const int* in_sizes, int n_in,
                              void* d_out, int out_size, void* d_ws, size_t ws_size,
                              hipStream_t stream) {
    (void)in_sizes; (void)n_in; (void)out_size;
    const float* f1 = (const float*)d_in[0];
    const float* f2 = (const float*)d_in[1];
    float* ws = (float*)d_ws;

    // common carve
    float* fiN  = ws;                                  // 2*9216*64
    float* frN  = fiN + NITEM * HW * C;                // 2*9216*64
    float* ssn  = frN + NITEM * HW * C;                // 2*9216
    float* invn = ssn + NITEM * HW;                    // 2*8836
    float* after = invn + NITEM * NP;
    size_t afterOff = ((size_t)(after - ws) + 63) & ~(size_t)63;

    // tier1: full-P carve (P = 2 * 9216 * 9216 floats = 680 MB)
    float* pmatF  = ws + afterOff;
    float* pbvF   = pmatF + (size_t)NITEM * HW * HW;
    int*   pbiF   = (int*)(pbvF + (size_t)NITEM * HP * NP);
    float* flowhF = (float*)(pbiF + (size_t)NITEM * HP * NP);
    float* flowwF = flowhF + NITEM * NP;
    size_t words_full = (size_t)(flowwF + NITEM * NP - ws);

    // tier2: banded carve (P band = 2 * 960 * 9216 floats = 70.8 MB)
    float* pmatB  = ws + afterOff;
    float* pbvB   = pmatB + (size_t)NITEM * PROWS_B * HW;
    int*   pbiB   = (int*)(pbvB + (size_t)NITEM * HP * NP);
    float* flowhB = (float*)(pbiB + (size_t)NITEM * HP * NP);
    float* flowwB = flowhB + NITEM * NP;
    size_t words_band = (size_t)(flowwB + NITEM * NP - ws);

    bool use_full = ws_size >= words_full * sizeof(float);
    bool use_band = ws_size >= words_band * sizeof(float);

    {
        int nthreads = 2 * NITEM * HW;
        normalize_kernel<<<(nthreads + 255) / 256, 256, 0, stream>>>(f1, f2, fiN, frN, ssn);
    }
    {
        int nthreads = NITEM * NP;
        refnorm_kernel<<<(nthreads + 255) / 256, 256, 0, stream>>>(ssn, invn);
    }

    if (use_full) {
        // 2 launches for the entire cost volume
        dim3 ga(NPT, NQT_F, NITEM);
        gemmP_kernel<<<ga, 512, 0, stream>>>(fiN, frN, pmatF, 0, HW);
        dim3 gb(HP, NIT, NITEM);
        pass2_kernel<<<gb, 256, 0, stream>>>(pmatF, invn, pbvF, pbiF, 0, HW);
        int nthreads = NITEM * NP;
        reduce94_kernel<<<(nthreads + 255) / 256, 256, 0, stream>>>(pbvF, pbiF, flowhF, flowwF);
        expand_kernel<<<(NITEM * 18 * HW + 255) / 256, 256, 0, stream>>>(flowhF, flowwF, (float*)d_out);
    } else if (use_band) {
        for (int b = 0; b < NBAND; b++) {
            int ry0 = b * BRY;
            int bryb = (HP - ry0 < BRY) ? (HP - ry0) : BRY;
            dim3 ga(NPT, NQT_B, NITEM);
            gemmP_kernel<<<ga, 512, 0, stream>>>(fiN, frN, pmatB, ry0, PROWS_B);
            dim3 gb(bryb, NIT, NITEM);
            pass2_kernel<<<gb, 256, 0, stream>>>(pmatB, invn, pbvB, pbiB, ry0, PROWS_B);
        }
        int nthreads = NITEM * NP;
        reduce94_kernel<<<(nthreads + 255) / 256, 256, 0, stream>>>(pbvB, pbiB, flowhB, flowwB);
        expand_kernel<<<(NITEM * 18 * HW + 255) / 256, 256, 0, stream>>>(flowhB, flowwB, (float*)d_out);
    } else {
        // fallback carve (fits ~10 MB)
        float* bestv = ws + afterOff;                       // 2*8*8836
        int*   besti = (int*)(bestv + NITEM * NSEG * NP);
        float* flowh = (float*)(besti + NITEM * NSEG * NP);
        float* floww = flowh + NITEM * NP;
        dim3 grid(NMTILE, NSEG, NITEM);
        corr_kernel<<<grid, 256, 0, stream>>>(fiN, frN, invn, bestv, besti);
        int nthreads = NITEM * NP;
        reduce_flow_kernel<<<(nthreads + 255) / 256, 256, 0, stream>>>(bestv, besti, flowh, floww);
        expand_kernel<<<(NITEM * 18 * HW + 255) / 256, 256, 0, stream>>>(flowh, floww, (float*)d_out);
    }
}

// Round 12
// 811.084 us; speedup vs baseline: 1.4078x; 1.4078x over previous
//
#include <hip/hip_runtime.h>
#include <math.h>

// Problem constants (N=2, C=64, H=96, W=96, PATCH=3)
static constexpr int NITEM = 2;
static constexpr int C = 64;
static constexpr int H = 96;
static constexpr int W = 96;
static constexpr int HW = H * W;         // 9216 pixels
static constexpr int HP = 94;            // H - 3 + 1
static constexpr int NP = HP * HP;       // 8836 patch positions

// ---- factored-path constants ----
static constexpr int BRY_L = 18;                    // large band: PYB=20 -> PROWS=1920 (15x128 exact)
static constexpr int PROWS_L = (BRY_L + 2) * W;     // 1920
static constexpr int BRY_S = 8;                     // small band fallback: PROWS=960
static constexpr int PROWS_S = (BRY_S + 2) * W;     // 960
static constexpr int TSP = 128;                     // tile edge
static constexpr int NPT = HW / TSP;                // 72 p-tiles (exact)
static constexpr int ITILE = 256;                   // i's per pass2 block
static constexpr int NIT = (NP + ITILE - 1) / ITILE; // 35
static constexpr int PAD = 132;                     // LDS row pad

// ---- fallback (R4 direct) constants ----
static constexpr int NSEG = 8;
static constexpr int SEGLEN = (NP + NSEG - 1) / NSEG; // 1105
static constexpr int MT = 128;
static constexpr int NT = 128;
static constexpr int KC = 16;
static constexpr int LDP = MT + 4;
static constexpr int NMTILE = (NP + MT - 1) / MT;   // 70

// ---------------- Kernel 1: per-pixel channel L2 normalize + NCHW->NHWC ----------------
__global__ __launch_bounds__(256) void normalize_kernel(
    const float* __restrict__ f1, const float* __restrict__ f2,
    float* __restrict__ fiN, float* __restrict__ frN, float* __restrict__ ssn)
{
    int t = blockIdx.x * 256 + threadIdx.x;
    const int perTensor = NITEM * HW;
    if (t >= 2 * perTensor) return;
    int which = t / perTensor;
    int p = t - which * perTensor;
    int n = p / HW;
    int pix = p - n * HW;
    const float* src = (which ? f2 : f1) + (size_t)n * C * HW + pix;
    float s = 0.f;
    #pragma unroll
    for (int c = 0; c < C; c++) {
        float v = src[c * HW];
        s = fmaf(v, v, s);
    }
    float norm = sqrtf(s);
    float scale = 1.0f / fmaxf(norm, 1e-12f);
    float* dst = (which ? frN : fiN) + (size_t)p * C;
    #pragma unroll
    for (int c = 0; c < C; c++) {
        dst[c] = src[c * HW] * scale;
    }
    if (which) ssn[p] = s * scale * scale;
}

// ---------------- Kernel 2: ref patch inverse norms ----------------
__global__ __launch_bounds__(256) void refnorm_kernel(
    const float* __restrict__ ssn, float* __restrict__ invn)
{
    int t = blockIdx.x * 256 + threadIdx.x;
    if (t >= NITEM * NP) return;
    int n = t / NP;
    int r = t - n * NP;
    int yr = r / HP, xr = r - yr * HP;
    const float* s = ssn + n * HW;
    float acc = 0.f;
    #pragma unroll
    for (int dy = 0; dy < 3; dy++)
        #pragma unroll
        for (int dx = 0; dx < 3; dx++)
            acc += s[(yr + dy) * W + (xr + dx)];
    invn[t] = 1.0f / (sqrtf(acc) + 1e-5f);
}

// ================= FACTORED PATH =================
// Kernel A (R10-proven 256-thread 8x8 version): GEMM writing RAW pixel-corr P[q][p].
// P[qL][p] = sum_c frN[ry0*W + qL][c] * fiN[p][c];  qL < prows.
// LDS-issue-bound: 4 ds_read_b128 per 64 FMA-inst per wave per k. The 512-thread
// 4x8 variant (R11) halved the FMA:LDS ratio on A-side and regressed 45->58 us.
__global__ __launch_bounds__(256) void gemmP_kernel(
    const float* __restrict__ fiN, const float* __restrict__ frN,
    float* __restrict__ pmat, int ry0, int prows)
{
    __shared__ struct { float Aq[C][PAD]; float Bp[C][PAD]; } sm;  // 67584 B

    const int t = threadIdx.x;
    const int pt0 = blockIdx.x * TSP;    // input-pixel col base (128-aligned)
    const int qt0 = blockIdx.y * TSP;    // P-local q base
    const int n = blockIdx.z;

    const float* fa = frN + (size_t)n * HW * C;  // q side (ref)
    const float* fb = fiN + (size_t)n * HW * C;  // p side (input)

    // ---- stage panels; channel map c0=(t&3)*4, cc=c0+16u -> LDS write 2-way max
    {
        const int lrow = t >> 2;
        const int c0 = (t & 3) * 4;
        #pragma unroll
        for (int rr = 0; rr < 2; rr++) {
            int m = lrow + rr * 64;
            int qpix = ry0 * W + qt0 + m; if (qpix > HW - 1) qpix = HW - 1;
            int ppix = pt0 + m;           if (ppix > HW - 1) ppix = HW - 1;
            const float* qa = fa + (size_t)qpix * C + c0;
            const float* pb = fb + (size_t)ppix * C + c0;
            #pragma unroll
            for (int u = 0; u < 4; u++) {
                float4 va = *(const float4*)(qa + 16 * u);
                float4 vb = *(const float4*)(pb + 16 * u);
                int cc = c0 + 16 * u;
                sm.Aq[cc + 0][m] = va.x; sm.Aq[cc + 1][m] = va.y;
                sm.Aq[cc + 2][m] = va.z; sm.Aq[cc + 3][m] = va.w;
                sm.Bp[cc + 0][m] = vb.x; sm.Bp[cc + 1][m] = vb.y;
                sm.Bp[cc + 2][m] = vb.z; sm.Bp[cc + 3][m] = vb.w;
            }
        }
    }
    __syncthreads();

    // ---- 128x128 GEMM, K=64. q slow across lanes (broadcast), p fast (coalesced stores).
    const int tmq = (t >> 4) * 4;   // q fragment base
    const int tnp = (t & 15) * 4;   // p fragment base
    float acc[8][8];
    #pragma unroll
    for (int i = 0; i < 8; i++)
        #pragma unroll
        for (int j = 0; j < 8; j++) acc[i][j] = 0.f;

    #pragma unroll 4
    for (int k = 0; k < C; k++) {
        float4 af0 = *(const float4*)&sm.Aq[k][tmq];
        float4 af1 = *(const float4*)&sm.Aq[k][tmq + 64];
        float4 bf0 = *(const float4*)&sm.Bp[k][tnp];
        float4 bf1 = *(const float4*)&sm.Bp[k][tnp + 64];
        float av[8] = {af0.x, af0.y, af0.z, af0.w, af1.x, af1.y, af1.z, af1.w};
        float bw[8] = {bf0.x, bf0.y, bf0.z, bf0.w, bf1.x, bf1.y, bf1.z, bf1.w};
        #pragma unroll
        for (int i = 0; i < 8; i++)
            #pragma unroll
            for (int j = 0; j < 8; j++)
                acc[i][j] = fmaf(av[i], bw[j], acc[i][j]);
    }

    // ---- direct register->global stores (two float4 per q-row), fully coalesced
    float* pn = pmat + (size_t)n * prows * HW;
    #pragma unroll
    for (int i = 0; i < 8; i++) {
        int qq = tmq + ((i < 4) ? i : 60 + i);
        int qL = qt0 + qq;
        if (qL < prows) {
            float* row = pn + (size_t)qL * HW + pt0;
            *(float4*)(row + tnp)      = make_float4(acc[i][0], acc[i][1], acc[i][2], acc[i][3]);
            *(float4*)(row + tnp + 64) = make_float4(acc[i][4], acc[i][5], acc[i][6], acc[i][7]);
        }
    }
}

// Kernel B: full 3x3 DIAGONAL sum from raw P + patch-norm scale + per-ry argmax.
// term(dy,dx) = P[(ryL+dy)*W + rx + dx][ppix + dy*W + dx] -> offset rx*HW + dx*(HW+1).
__global__ __launch_bounds__(256) void pass2_kernel(
    const float* __restrict__ pmat, const float* __restrict__ invn,
    float* __restrict__ pbv, int* __restrict__ pbi, int ry0, int prows)
{
    const int t = threadIdx.x;
    const int ryL = blockIdx.x;          // P-local ref patch-row
    const int ry = ry0 + ryL;            // global ref patch-row
    const int n = blockIdx.z;
    const int i = blockIdx.y * ITILE + t;
    if (i >= NP) return;

    const float* pn = pmat + (size_t)n * prows * HW;
    const float* inv = invn + (size_t)n * NP + ry * HP;
    const int rBase = ry * HP;

    int iy = i / HP, ix = i - iy * HP;
    int ppix = iy * W + ix;
    const float* b0 = pn + (size_t)(ryL * W) * HW + ppix;
    const float* b1 = b0 + (size_t)W * HW + W;
    const float* b2 = b1 + (size_t)W * HW + W;
    const size_t D = (size_t)HW + 1;     // diagonal stride (+1 row, +1 col)

    float bv = -INFINITY;
    int brx = 0;
    #pragma unroll 2
    for (int rx = 0; rx < HP; rx++) {
        size_t o = (size_t)rx * HW;
        float s0 = (b0[o] + b0[o + D]) + b0[o + 2 * D];
        float s1 = (b1[o] + b1[o + D]) + b1[o + 2 * D];
        float s2 = (b2[o] + b2[o + D]) + b2[o + 2 * D];
        float v = ((s0 + s1) + s2) * inv[rx];
        if (v > bv) { bv = v; brx = rx; }
    }
    size_t o = ((size_t)n * HP + ry) * NP + i;
    pbv[o] = bv;
    pbi[o] = rBase + brx;
}

// Reduce over 94 ry partials -> flow (lexicographic: first global max)
__global__ __launch_bounds__(256) void reduce94_kernel(
    const float* __restrict__ pbv, const int* __restrict__ pbi,
    float* __restrict__ flowh, float* __restrict__ floww)
{
    int t = blockIdx.x * 256 + threadIdx.x;
    if (t >= NITEM * NP) return;
    int n = t / NP;
    int i = t - n * NP;
    const float* bvp = pbv + (size_t)n * HP * NP;
    const int* bip = pbi + (size_t)n * HP * NP;
    float v = bvp[i];
    int idx = bip[i];
    for (int s = 1; s < HP; s++) {
        float v2 = bvp[(size_t)s * NP + i];
        int i2 = bip[(size_t)s * NP + i];
        if (v2 > v || (v2 == v && i2 < idx)) { v = v2; idx = i2; }
    }
    int yi = i / HP, xi = i - yi * HP;
    int yr = idx / HP, xr = idx - yr * HP;
    flowh[t] = (float)(yr - yi);
    floww[t] = (float)(xr - xi);
}

// ================= FALLBACK PATH (R4 direct, proven) =================
__global__ __launch_bounds__(256) void corr_kernel(
    const float* __restrict__ fiN, const float* __restrict__ frN,
    const float* __restrict__ invn,
    float* __restrict__ bestv, int* __restrict__ besti)
{
    __shared__ union SM {
        struct { float A[KC][LDP]; float B[KC][LDP]; } g;
        struct { float rv[MT][16]; int ri[MT][16]; } red;
    } sm;

    const int t = threadIdx.x;
    const int itile = blockIdx.x;
    const int seg = blockIdx.y;
    const int n = blockIdx.z;

    const float* fa = fiN + (size_t)n * HW * C;
    const float* fb = frN + (size_t)n * HW * C;
    const float* inv = invn + (size_t)n * NP;

    const int lrow = t >> 2;
    const int lc = (t & 3) * 4;

    int ia0 = itile * MT + lrow;      if (ia0 > NP - 1) ia0 = NP - 1;
    int ia1 = itile * MT + lrow + 64; if (ia1 > NP - 1) ia1 = NP - 1;
    const int ay0 = ia0 / HP, ax0 = ia0 - ay0 * HP;
    const int ay1 = ia1 / HP, ax1 = ia1 - ay1 * HP;
    const int aoff0 = (ay0 * W + ax0) * C;
    const int aoff1 = (ay1 * W + ax1) * C;

    const int tm4 = (t & 15) * 4;
    const int tn4 = (t >> 4) * 4;

    const int segStart = seg * SEGLEN;
    const int segEnd = (segStart + SEGLEN < NP) ? segStart + SEGLEN : NP;

    float bv[8];
    int bi[8];
    #pragma unroll
    for (int i = 0; i < 8; i++) { bv[i] = -INFINITY; bi[i] = 0; }

    for (int rt = segStart; rt < segEnd; rt += NT) {
        int ib0 = rt + lrow;      if (ib0 > NP - 1) ib0 = NP - 1;
        int ib1 = rt + lrow + 64; if (ib1 > NP - 1) ib1 = NP - 1;
        const int by0 = ib0 / HP, bx0 = ib0 - by0 * HP;
        const int by1 = ib1 / HP, bx1 = ib1 - by1 * HP;
        const int boff0 = (by0 * W + bx0) * C;
        const int boff1 = (by1 * W + bx1) * C;

        float acc[8][8];
        #pragma unroll
        for (int i = 0; i < 8; i++)
            #pragma unroll
            for (int j = 0; j < 8; j++) acc[i][j] = 0.f;

        float4 a0 = *(const float4*)(fa + aoff0 + lc);
        float4 a1 = *(const float4*)(fa + aoff1 + lc);
        float4 b0 = *(const float4*)(fb + boff0 + lc);
        float4 b1 = *(const float4*)(fb + boff1 + lc);

        #pragma unroll 1
        for (int ch = 0; ch < 36; ch++) {
            __syncthreads();
            sm.g.A[lc + 0][lrow] = a0.x; sm.g.A[lc + 1][lrow] = a0.y;
            sm.g.A[lc + 2][lrow] = a0.z; sm.g.A[lc + 3][lrow] = a0.w;
            sm.g.A[lc + 0][lrow + 64] = a1.x; sm.g.A[lc + 1][lrow + 64] = a1.y;
            sm.g.A[lc + 2][lrow + 64] = a1.z; sm.g.A[lc + 3][lrow + 64] = a1.w;
            sm.g.B[lc + 0][lrow] = b0.x; sm.g.B[lc + 1][lrow] = b0.y;
            sm.g.B[lc + 2][lrow] = b0.z; sm.g.B[lc + 3][lrow] = b0.w;
            sm.g.B[lc + 0][lrow + 64] = b1.x; sm.g.B[lc + 1][lrow + 64] = b1.y;
            sm.g.B[lc + 2][lrow + 64] = b1.z; sm.g.B[lc + 3][lrow + 64] = b1.w;
            __syncthreads();

            if (ch < 35) {
                const int chn = ch + 1;
                const int pp = chn >> 2;
                const int c0 = (chn & 3) << 4;
                const int dy = pp / 3, dx = pp - dy * 3;
                const int poff = (dy * W + dx) * C + c0 + lc;
                a0 = *(const float4*)(fa + aoff0 + poff);
                a1 = *(const float4*)(fa + aoff1 + poff);
                b0 = *(const float4*)(fb + boff0 + poff);
                b1 = *(const float4*)(fb + boff1 + poff);
            }

            #pragma unroll
            for (int k = 0; k < KC; k++) {
                float4 af0 = *(const float4*)&sm.g.A[k][tm4];
                float4 af1 = *(const float4*)&sm.g.A[k][tm4 + 64];
                float4 bf0 = *(const float4*)&sm.g.B[k][tn4];
                float4 bf1 = *(const float4*)&sm.g.B[k][tn4 + 64];
                float av[8] = {af0.x, af0.y, af0.z, af0.w, af1.x, af1.y, af1.z, af1.w};
                float bw[8] = {bf0.x, bf0.y, bf0.z, bf0.w, bf1.x, bf1.y, bf1.z, bf1.w};
                #pragma unroll
                for (int i = 0; i < 8; i++)
                    #pragma unroll
                    for (int j = 0; j < 8; j++)
                        acc[i][j] = fmaf(av[i], bw[j], acc[i][j]);
            }
        }

        #pragma unroll
        for (int j = 0; j < 8; j++) {
            int col = tn4 + ((j < 4) ? j : 60 + j);
            int r = rt + col;
            bool valid = (r < segEnd);
            float iv = inv[valid ? r : 0];
            #pragma unroll
            for (int i = 0; i < 8; i++) {
                float v = acc[i][j] * iv;
                if (valid && v > bv[i]) { bv[i] = v; bi[i] = r; }
            }
        }
    }

    __syncthreads();
    #pragma unroll
    for (int i = 0; i < 8; i++) {
        int row = tm4 + ((i < 4) ? i : 60 + i);
        sm.red.rv[row][t >> 4] = bv[i];
        sm.red.ri[row][t >> 4] = bi[i];
    }
    __syncthreads();
    if (t < MT) {
        float v = sm.red.rv[t][0];
        int idx = sm.red.ri[t][0];
        #pragma unroll
        for (int j = 1; j < 16; j++) {
            float v2 = sm.red.rv[t][j];
            int i2 = sm.red.ri[t][j];
            if (v2 > v || (v2 == v && i2 < idx)) { v = v2; idx = i2; }
        }
        int gi = itile * MT + t;
        if (gi < NP) {
            size_t o = ((size_t)n * NSEG + seg) * NP + gi;
            bestv[o] = v;
            besti[o] = idx;
        }
    }
}

__global__ __launch_bounds__(256) void reduce_flow_kernel(
    const float* __restrict__ bestv, const int* __restrict__ besti,
    float* __restrict__ flowh, float* __restrict__ floww)
{
    int t = blockIdx.x * 256 + threadIdx.x;
    if (t >= NITEM * NP) return;
    int n = t / NP;
    int i = t - n * NP;
    const float* bvp = bestv + (size_t)n * NSEG * NP;
    const int* bip = besti + (size_t)n * NSEG * NP;
    float v = bvp[i];
    int idx = bip[i];
    #pragma unroll
    for (int s = 1; s < NSEG; s++) {
        float v2 = bvp[s * NP + i];
        int i2 = bip[s * NP + i];
        if (v2 > v || (v2 == v && i2 < idx)) { v = v2; idx = i2; }
    }
    int yi = i / HP, xi = i - yi * HP;
    int yr = idx / HP, xr = idx - yr * HP;
    flowh[t] = (float)(yr - yi);
    floww[t] = (float)(xr - xi);
}

// ---------------- Kernel 5: expand to 9 shifted copies, channel-interleaved ----------------
__global__ __launch_bounds__(256) void expand_kernel(
    const float* __restrict__ flowh, const float* __restrict__ floww,
    float* __restrict__ out)
{
    int t = blockIdx.x * 256 + threadIdx.x;
    const int total = NITEM * 18 * HW;
    if (t >= total) return;
    int x = t % W;
    int y = (t / W) % H;
    int chn = (t / HW) % 18;
    int n = t / (18 * HW);
    int k = chn >> 1;
    int b = chn & 1;
    int is = k / 3, js = k - is * 3;
    int ys = y - is, xs = x - js;
    float val = 0.f;
    if (ys >= 0 && ys < HP && xs >= 0 && xs < HP) {
        int src = n * NP + ys * HP + xs;
        val = b ? floww[src] : flowh[src];
    }
    out[t] = val;
}

// ---------------- Launch ----------------
extern "C" void kernel_launch(void* const* d_in, const int* in_sizes, int n_in,
                              void* d_out, int out_size, void* d_ws, size_t ws_size,
                              hipStream_t stream) {
    (void)in_sizes; (void)n_in; (void)out_size;
    const float* f1 = (const float*)d_in[0];
    const float* f2 = (const float*)d_in[1];
    float* ws = (float*)d_ws;

    // common carve
    float* fiN  = ws;                                  // 2*9216*64
    float* frN  = fiN + NITEM * HW * C;                // 2*9216*64
    float* ssn  = frN + NITEM * HW * C;                // 2*9216
    float* invn = ssn + NITEM * HW;                    // 2*8836
    float* after = invn + NITEM * NP;
    size_t afterOff = ((size_t)(after - ws) + 63) & ~(size_t)63;

    // helper sizes (in floats)
    size_t partials = (size_t)NITEM * HP * NP;         // pbv (and pbi as ints)
    size_t tailWords = partials * 2 + (size_t)NITEM * NP * 2;

    // tier carve: pmat + pbv + pbi + flowh + floww
    float* pmat  = ws + afterOff;
    auto tier_words = [&](size_t prowsT) {
        return afterOff + (size_t)NITEM * prowsT * HW + tailWords;
    };
    bool use_full = ws_size >= tier_words(HW) * sizeof(float);
    bool use_l    = ws_size >= tier_words(PROWS_L) * sizeof(float);
    bool use_s    = ws_size >= tier_words(PROWS_S) * sizeof(float);

    {
        int nthreads = 2 * NITEM * HW;
        normalize_kernel<<<(nthreads + 255) / 256, 256, 0, stream>>>(f1, f2, fiN, frN, ssn);
    }
    {
        int nthreads = NITEM * NP;
        refnorm_kernel<<<(nthreads + 255) / 256, 256, 0, stream>>>(ssn, invn);
    }

    if (use_full || use_l || use_s) {
        int prowsT = use_full ? HW : (use_l ? PROWS_L : PROWS_S);
        int bry    = use_full ? HP : (use_l ? BRY_L : BRY_S);
        float* pbv   = pmat + (size_t)NITEM * prowsT * HW;
        int*   pbi   = (int*)(pbv + partials);
        float* flowh = (float*)(pbi + partials);
        float* floww = flowh + NITEM * NP;

        for (int ry0 = 0; ry0 < HP; ry0 += bry) {
            int bryb = (HP - ry0 < bry) ? (HP - ry0) : bry;
            int prows_used = use_full ? HW : (bryb + 2) * W;
            int nqt = (prows_used + TSP - 1) / TSP;
            dim3 ga(NPT, nqt, NITEM);
            gemmP_kernel<<<ga, 256, 0, stream>>>(fiN, frN, pmat, ry0, prows_used);
            dim3 gb(bryb, NIT, NITEM);
            pass2_kernel<<<gb, 256, 0, stream>>>(pmat, invn, pbv, pbi, ry0, prows_used);
        }
        int nthreads = NITEM * NP;
        reduce94_kernel<<<(nthreads + 255) / 256, 256, 0, stream>>>(pbv, pbi, flowh, floww);
        expand_kernel<<<(NITEM * 18 * HW + 255) / 256, 256, 0, stream>>>(flowh, floww, (float*)d_out);
    } else {
        // direct fallback carve (fits ~10 MB)
        float* bestv = ws + afterOff;                       // 2*8*8836
        int*   besti = (int*)(bestv + NITEM * NSEG * NP);
        float* flowh = (float*)(besti + NITEM * NSEG * NP);
        float* floww = flowh + NITEM * NP;
        dim3 grid(NMTILE, NSEG, NITEM);
        corr_kernel<<<grid, 256, 0, stream>>>(fiN, frN, invn, bestv, besti);
        int nthreads = NITEM * NP;
        reduce_flow_kernel<<<(nthreads + 255) / 256, 256, 0, stream>>>(bestv, besti, flowh, floww);
        expand_kernel<<<(NITEM * 18 * HW + 255) / 256, 256, 0, stream>>>(flowh, floww, (float*)d_out);
    }
}